// Round 20
// baseline (428.502 us; speedup 1.0000x reference)
//
#include <hip/hip_runtime.h>
#include <hip/hip_bf16.h>

typedef unsigned short u16;
typedef unsigned int u32;
typedef __attribute__((ext_vector_type(8))) short s16x8;
typedef __attribute__((ext_vector_type(4))) float f32x4;

__device__ __forceinline__ u16 f2b(float v) {
  u32 bits = __float_as_uint(v);
  bits += 0x7fffu + ((bits >> 16) & 1u);
  return (u16)(bits >> 16);
}
__device__ __forceinline__ float b2f(u16 u) { return __uint_as_float(((u32)u) << 16); }
__device__ __forceinline__ float bflo(u32 w) { return __uint_as_float(w << 16); }
__device__ __forceinline__ float bfhi(u32 w) { return __uint_as_float(w & 0xffff0000u); }

// ---------------- LayerNorm (LN2): bf16-only outputs x1b (ch0..31), x2h (ch32..63)
__global__ __launch_bounds__(256) void k_ln2(const float* __restrict__ x, const float* __restrict__ g,
    const float* __restrict__ b, u16* __restrict__ x1b, u16* __restrict__ x2h) {
  int token = blockIdx.x * 4 + (threadIdx.x >> 6);
  int lane = threadIdx.x & 63;
  long base = (long)token * 64 + lane;
  float v = x[base];
  float s = v;
#pragma unroll
  for (int o = 32; o; o >>= 1) s += __shfl_xor(s, o);
  float m = s * 0.015625f;
  float d = v - m;
  float q = d * d;
#pragma unroll
  for (int o = 32; o; o >>= 1) q += __shfl_xor(q, o);
  float r = rsqrtf(q * 0.015625f + 1e-5f);
  float hv = d * r * g[lane] + b[lane];
  u16 hb = f2b(hv);
  if (lane < 32) x1b[(long)token * 32 + lane] = hb;
  else x2h[(long)token * 32 + lane - 32] = hb;
}

// ---------------- Small prepacks (d_out scratch): pwb|twb|swb|Bt ----------------
__global__ __launch_bounds__(256) void k_prep(const float* __restrict__ pw, u16* __restrict__ pwb,
    const float* __restrict__ tqw, u16* __restrict__ twb,
    const float* __restrict__ sqw, u16* __restrict__ swb,
    const float* __restrict__ rpb, float* __restrict__ Bt) {
  int i = blockIdx.x * 256 + threadIdx.x;
  if (i < 4096) {
    int r = i & 7, q = i >> 3;
    int col = q & 15; q >>= 4;
    int lk = q & 1; q >>= 1;
    int nt = q & 3, hd = q >> 2;
    pwb[i] = f2b(pw[(hd * 16 + lk * 8 + r) * 64 + nt * 16 + col]);
  } else if (i < 10240) {
    int j = i - 4096;
    int kk = j & 31, q = j >> 5;
    int lm = q & 15, ksnt = q >> 4;
    int ks = ksnt & 1, nt = ksnt >> 1;
    twb[j] = f2b(tqw[(ks * 32 + kk) * 96 + nt * 16 + lm]);
  } else if (i < 22528) {
    int j = i - 10240;
    int kk = j & 31, q = j >> 5;
    int lm = q & 15, ksnt = q >> 4;
    int ks = ksnt & 1, nt = ksnt >> 1;
    swb[j] = f2b(sqw[(ks * 32 + kk) * 192 + nt * 16 + lm]);
  } else {
    int j = i - 22528;
    int m = j % 112, q = j / 112;
    int n = q % 112, hd = q / 112;
    float v = -1e30f;
    if (n < 98 && m < 98) {
      int dzn = n / 49, rn = n % 49, hyn = rn / 7, wxn = rn % 7;
      int dzm = m / 49, rm = m % 49, hym = rm / 7, wxm = rm % 7;
      int idx = (dzn - dzm + 1) * 169 + (hyn - hym + 6) * 13 + (wxn - wxm + 6);
      v = rpb[idx * 4 + hd];
    }
    Bt[j] = v;
  }
}

// ---------------- Conv weight prepack: MUST run after Vg is dead ----------------
__global__ __launch_bounds__(256) void k_wprep(const float* __restrict__ w0, const float* __restrict__ w1,
    const float* __restrict__ w2, const float* __restrict__ w3, u16* __restrict__ WB) {
  int j = blockIdx.x * 256 + threadIdx.x;   // < 110592
  int c = j / 27648, j2 = j - c * 27648;
  const float* src = c == 0 ? w0 : c == 1 ? w1 : c == 2 ? w2 : w3;
  int co = j2 / 864, rem = j2 - co * 864, ci = rem / 27, kk = rem - ci * 27;
  WB[c * 27648 + kk * 1024 + co * 32 + ci] = f2b(src[j2]);
}

// ---------------- Fused LN1 + spatial qkv + temporal qkv (MFMA) -----------------
__global__ __launch_bounds__(256) void k_fused1(const float* __restrict__ x,
    const float* __restrict__ g1, const float* __restrict__ b1,
    const u16* __restrict__ swb, const float* __restrict__ sqb,
    const u16* __restrict__ twb, const float* __restrict__ tqb,
    float* __restrict__ acc, u16* __restrict__ Qg, u16* __restrict__ Kg,
    u16* __restrict__ Vg, u16* __restrict__ T) {
  int l = threadIdx.x & 63, wv = threadIdx.x >> 6;
  int lm = l & 15, lk = l >> 4;
  long t0 = (long)blockIdx.x * 64 + wv * 16;
  long tok = t0 + lm;
  const float* xp = x + tok * 64 + lk * 8;
  float* ap = acc + tok * 64 + lk * 8;
  float va[16];
  float s = 0.f;
#pragma unroll
  for (int ks = 0; ks < 2; ks++) {
    float4 a0 = *(const float4*)(xp + ks * 32);
    float4 a1 = *(const float4*)(xp + ks * 32 + 4);
    *(float4*)(ap + ks * 32) = a0;          // acc = x
    *(float4*)(ap + ks * 32 + 4) = a1;
    va[ks * 8 + 0] = a0.x; va[ks * 8 + 1] = a0.y; va[ks * 8 + 2] = a0.z; va[ks * 8 + 3] = a0.w;
    va[ks * 8 + 4] = a1.x; va[ks * 8 + 5] = a1.y; va[ks * 8 + 6] = a1.z; va[ks * 8 + 7] = a1.w;
    s += a0.x + a0.y + a0.z + a0.w + a1.x + a1.y + a1.z + a1.w;
  }
  s += __shfl_xor(s, 16); s += __shfl_xor(s, 32);
  float m = s * 0.015625f;
  float q = 0.f;
#pragma unroll
  for (int j = 0; j < 16; j++) { float d = va[j] - m; q += d * d; }
  q += __shfl_xor(q, 16); q += __shfl_xor(q, 32);
  float r = rsqrtf(q * 0.015625f + 1e-5f);
  s16x8 A[2];
#pragma unroll
  for (int ks = 0; ks < 2; ks++) {
    float4 g0 = *(const float4*)(g1 + ks * 32 + lk * 8);
    float4 g4 = *(const float4*)(g1 + ks * 32 + lk * 8 + 4);
    float4 c0 = *(const float4*)(b1 + ks * 32 + lk * 8);
    float4 c4 = *(const float4*)(b1 + ks * 32 + lk * 8 + 4);
    s16x8 a;
    a[0] = (short)f2b((va[ks * 8 + 0] - m) * r * g0.x + c0.x);
    a[1] = (short)f2b((va[ks * 8 + 1] - m) * r * g0.y + c0.y);
    a[2] = (short)f2b((va[ks * 8 + 2] - m) * r * g0.z + c0.z);
    a[3] = (short)f2b((va[ks * 8 + 3] - m) * r * g0.w + c0.w);
    a[4] = (short)f2b((va[ks * 8 + 4] - m) * r * g4.x + c4.x);
    a[5] = (short)f2b((va[ks * 8 + 5] - m) * r * g4.y + c4.y);
    a[6] = (short)f2b((va[ks * 8 + 6] - m) * r * g4.z + c4.z);
    a[7] = (short)f2b((va[ks * 8 + 7] - m) * r * g4.w + c4.w);
    A[ks] = a;
  }
  f32x4 C[12], D[6];
#pragma unroll
  for (int nt = 0; nt < 12; nt++) C[nt] = (f32x4){0.f, 0.f, 0.f, 0.f};
#pragma unroll
  for (int nt = 0; nt < 6; nt++) D[nt] = (f32x4){0.f, 0.f, 0.f, 0.f};
#pragma unroll
  for (int ks = 0; ks < 2; ks++) {
#pragma unroll
    for (int nt = 0; nt < 12; nt++) {
      s16x8 B = *(const s16x8*)&swb[((nt * 2 + ks) * 16 + lm) * 32 + lk * 8];
      C[nt] = __builtin_amdgcn_mfma_f32_16x16x32_bf16(A[ks], B, C[nt], 0, 0, 0);
    }
#pragma unroll
    for (int nt = 0; nt < 6; nt++) {
      s16x8 B = *(const s16x8*)&twb[((nt * 2 + ks) * 16 + lm) * 32 + lk * 8];
      D[nt] = __builtin_amdgcn_mfma_f32_16x16x32_bf16(A[ks], B, D[nt], 0, 0, 0);
    }
  }
  float sbv[12], tbv[6];
#pragma unroll
  for (int nt = 0; nt < 12; nt++) sbv[nt] = sqb[nt * 16 + lm];
#pragma unroll
  for (int nt = 0; nt < 6; nt++) tbv[nt] = tqb[nt * 16 + lm];
#pragma unroll
  for (int r4 = 0; r4 < 4; r4++) {
    long t = t0 + lk * 4 + r4;
    int b = (int)(t / 100352); int r1 = (int)(t - (long)b * 100352);
    int d = r1 / 12544; int r2 = r1 - d * 12544;
    int hy = r2 / 112, wx = r2 - hy * 112;
    int d0 = d >> 1, dz = d & 1, h0 = hy / 7, oy = hy - h0 * 7, w0 = wx / 7, ox = wx - w0 * 7;
    int wi = ((b * 4 + d0) * 16 + h0) * 16 + w0;
    int n = dz * 49 + oy * 7 + ox;
    long sbase = (long)(wi * 4) * 1568 + n * 16 + lm;
#pragma unroll
    for (int nt = 0; nt < 12; nt++) {
      int part = nt >> 2, hd = nt & 3;
      float v = C[nt][r4] + sbv[nt];
      long o = sbase + hd * 1568;
      if (part == 0) Qg[o] = f2b(v * 0.25f);
      else if (part == 1) Kg[o] = f2b(v);
      else Vg[o] = f2b(v);
    }
    long sidx = ((long)(b * 12544 + r2) * 8 + d) * 96;
#pragma unroll
    for (int nt = 0; nt < 6; nt++) {
      float v = D[nt][r4] + tbv[nt];
      if (nt < 2) v *= 0.25f;
      T[sidx + nt * 16 + lm] = f2b(v);
    }
  }
}

// ---------------- MFMA spatial attention + fused projection ---------------------
// Heads processed in PAIRS: K/V double-buffered by head -> 4 barriers total (was 8),
// longer compute phases, better VMEM pipelining. Q direct from global (r17 proven).
__global__ __launch_bounds__(512) void k_sattn3(const u16* __restrict__ Qg, const u16* __restrict__ Kg,
    const u16* __restrict__ Vg, const float* __restrict__ Bt, const u16* __restrict__ pwb,
    const float* __restrict__ pb, float* __restrict__ accg) {
  __shared__ __align__(16) u16 sK[2][112 * 24];
  __shared__ __align__(16) u16 sVt[2][16 * 136];
  __shared__ __align__(16) u16 sP[112 * 120 + 32];
  __shared__ __align__(16) u16 sO[112 * 24];
  int tid = threadIdx.x;
  int wi = blockIdx.x;
  int l = tid & 63, wv = tid >> 6;
  int lm = l & 15, lk = l >> 4;

  for (int i = tid; i < 336; i += 512) { sK[0][2352 + i] = 0; sK[1][2352 + i] = 0; }
  for (int i = tid; i < 224; i += 512) {
    int idx = (i / 14) * 136 + 98 + (i % 14);
    sVt[0][idx] = 0; sVt[1][idx] = 0;
  }

  int mt = wv;
  bool act = mt < 7;
  int baserow = mt * 16 + lk * 4;
  int qrow = mt * 16 + lm;
  f32x4 po[4];
#pragma unroll
  for (int b = 0; b < 4; b++) po[b] = (f32x4){0.f, 0.f, 0.f, 0.f};

  for (int pair = 0; pair < 2; pair++) {
    __syncthreads();
    long base0 = (long)(wi * 4 + pair * 2) * 1568;
#pragma unroll
    for (int hp = 0; hp < 2; hp++) {
      const u32* kp = (const u32*)(Kg + base0 + hp * 1568);
      for (int i = tid; i < 784; i += 512) {
        u32 v = kp[i];
        int n = i >> 3, j2 = (i & 7) * 2;
        *(u32*)&sK[hp][n * 24 + j2] = v;
      }
    }
#pragma unroll
    for (int hp = 0; hp < 2; hp++) {
      const u32* vp = (const u32*)(Vg + base0 + hp * 1568);
      for (int i = tid; i < 784; i += 512) {
        u32 v = vp[i];
        int n = i >> 3, j2 = (i & 7) * 2;
        sVt[hp][j2 * 136 + n] = (u16)(v & 0xffffu);
        sVt[hp][(j2 + 1) * 136 + n] = (u16)(v >> 16);
      }
    }
    __syncthreads();
    if (!act) continue;

#pragma unroll
    for (int hp = 0; hp < 2; hp++) {
      int hd = pair * 2 + hp;
      long base = base0 + hp * 1568;
      s16x8 Aq = {};
      if (qrow < 98 && lk < 2) Aq = *(const s16x8*)(Qg + base + qrow * 16 + lk * 8);
      f32x4 S[7];
#pragma unroll
      for (int nt = 0; nt < 7; nt++) {
        s16x8 Bk = {};
        if (lk < 2) Bk = *(const s16x8*)&sK[hp][(nt * 16 + lm) * 24 + lk * 8];
        S[nt] = __builtin_amdgcn_mfma_f32_16x16x32_bf16(Aq, Bk, (f32x4){0.f, 0.f, 0.f, 0.f}, 0, 0, 0);
      }
      const float* bt = Bt + hd * 12544 + baserow * 112 + lm;
      float mx0 = -3e38f, mx1 = -3e38f, mx2 = -3e38f, mx3 = -3e38f;
#pragma unroll
      for (int nt = 0; nt < 7; nt++) {
        S[nt][0] += bt[nt * 16];
        S[nt][1] += bt[112 + nt * 16];
        S[nt][2] += bt[224 + nt * 16];
        S[nt][3] += bt[336 + nt * 16];
        mx0 = fmaxf(mx0, S[nt][0]); mx1 = fmaxf(mx1, S[nt][1]);
        mx2 = fmaxf(mx2, S[nt][2]); mx3 = fmaxf(mx3, S[nt][3]);
      }
#pragma unroll
      for (int off = 1; off < 16; off <<= 1) {
        mx0 = fmaxf(mx0, __shfl_xor(mx0, off));
        mx1 = fmaxf(mx1, __shfl_xor(mx1, off));
        mx2 = fmaxf(mx2, __shfl_xor(mx2, off));
        mx3 = fmaxf(mx3, __shfl_xor(mx3, off));
      }
      float s0 = 0.f, s1 = 0.f, s2 = 0.f, s3 = 0.f;
#pragma unroll
      for (int nt = 0; nt < 7; nt++) {
        S[nt][0] = __expf(S[nt][0] - mx0); s0 += S[nt][0];
        S[nt][1] = __expf(S[nt][1] - mx1); s1 += S[nt][1];
        S[nt][2] = __expf(S[nt][2] - mx2); s2 += S[nt][2];
        S[nt][3] = __expf(S[nt][3] - mx3); s3 += S[nt][3];
      }
#pragma unroll
      for (int off = 1; off < 16; off <<= 1) {
        s0 += __shfl_xor(s0, off); s1 += __shfl_xor(s1, off);
        s2 += __shfl_xor(s2, off); s3 += __shfl_xor(s3, off);
      }
      float i0 = 1.f / s0, i1 = 1.f / s1, i2 = 1.f / s2, i3 = 1.f / s3;
#pragma unroll
      for (int nt = 0; nt < 7; nt++) {
        int c = nt * 16 + lm;
        sP[(baserow + 0) * 120 + c] = f2b(S[nt][0] * i0);
        sP[(baserow + 1) * 120 + c] = f2b(S[nt][1] * i1);
        sP[(baserow + 2) * 120 + c] = f2b(S[nt][2] * i2);
        sP[(baserow + 3) * 120 + c] = f2b(S[nt][3] * i3);
      }
      int rowoff = (mt * 16 + lm) * 120;
      f32x4 pv = (f32x4){0.f, 0.f, 0.f, 0.f};
#pragma unroll
      for (int ks = 0; ks < 3; ks++) {
        s16x8 Ap = *(const s16x8*)&sP[rowoff + ks * 32 + lk * 8];
        s16x8 Bv = *(const s16x8*)&sVt[hp][lm * 136 + ks * 32 + lk * 8];
        pv = __builtin_amdgcn_mfma_f32_16x16x32_bf16(Ap, Bv, pv, 0, 0, 0);
      }
      {
        s16x8 Ap = {}, Bv = {};
        if (lk < 2) {
          Ap = *(const s16x8*)&sP[rowoff + 96 + lk * 8];
          Bv = *(const s16x8*)&sVt[hp][lm * 136 + 96 + lk * 8];
        }
        pv = __builtin_amdgcn_mfma_f32_16x16x32_bf16(Ap, Bv, pv, 0, 0, 0);
      }
#pragma unroll
      for (int r = 0; r < 4; r++) sO[(baserow + r) * 24 + lm] = f2b(pv[r]);
      s16x8 Ao = {};
      if (lk < 2) Ao = *(const s16x8*)&sO[(mt * 16 + lm) * 24 + lk * 8];
#pragma unroll
      for (int nt = 0; nt < 4; nt++) {
        s16x8 Bw = {};
        if (lk < 2) Bw = *(const s16x8*)&pwb[((((hd * 4 + nt) * 2 + lk) * 16 + lm) * 8)];
        po[nt] = __builtin_amdgcn_mfma_f32_16x16x32_bf16(Ao, Bw, po[nt], 0, 0, 0);
      }
    }
  }
  if (act) {
    int b = wi >> 10, d0 = (wi >> 8) & 3, h0 = (wi >> 4) & 15, w0 = wi & 15;
    float pbv[4];
#pragma unroll
    for (int nt = 0; nt < 4; nt++) pbv[nt] = pb[nt * 16 + lm];
#pragma unroll
    for (int r = 0; r < 4; r++) {
      int n = mt * 16 + lk * 4 + r;
      if (n >= 98) continue;
      int dz = n / 49, rr = n - dz * 49, oy = rr / 7, ox = rr - oy * 7;
      long p = ((long)(b * 8 + d0 * 2 + dz) * 112 + (h0 * 7 + oy)) * 112 + (w0 * 7 + ox);
      float* ap = accg + p * 64;
#pragma unroll
      for (int nt = 0; nt < 4; nt++) {
        int col = nt * 16 + lm;
        ap[col] += po[nt][r] + pbv[nt];
      }
    }
  }
}

// ---------------- Temporal attention (per pixel-seq, D=8) + proj, acc += --------
__global__ __launch_bounds__(256) void k_tattn2(const u16* __restrict__ T, const float* __restrict__ rpbt,
    const float* __restrict__ pw, const float* __restrict__ pb, float* __restrict__ acc) {
  __shared__ float sm[4][1064];   // sq 8x100, o 8x33
  int wv = threadIdx.x >> 6, lane = threadIdx.x & 63;
  int s = blockIdx.x * 4 + wv;
  int b = s / 12544, rr = s - b * 12544;
  float* sq = sm[wv];
  float* o = sq + 800;
  const u32* Tp = (const u32*)(T + (long)s * 768);
  for (int i = lane; i < 192; i += 64) {
    u32 lo = Tp[i * 2], hi = Tp[i * 2 + 1];
    int d = i / 24, base = (i - d * 24) * 4;
    float* dst = sq + d * 100 + base;
    dst[0] = bflo(lo); dst[1] = bfhi(lo); dst[2] = bflo(hi); dst[3] = bfhi(hi);
  }
  __syncthreads();
  if (lane < 32) {
    int hd = lane >> 3, n = lane & 7;
    const float* qr = sq + n * 100 + hd * 8;
    float p[8];
    float mx = -3e38f;
#pragma unroll
    for (int m = 0; m < 8; m++) {
      const float* kr = sq + m * 100 + 32 + hd * 8;
      float sc = 0.f;
#pragma unroll
      for (int e = 0; e < 8; e++) sc += qr[e] * kr[e];
      sc += rpbt[(n - m + 7) * 4 + hd];
      p[m] = sc; mx = fmaxf(mx, sc);
    }
    float sum = 0.f;
#pragma unroll
    for (int m = 0; m < 8; m++) { p[m] = __expf(p[m] - mx); sum += p[m]; }
    float inv = 1.f / sum;
#pragma unroll
    for (int j = 0; j < 8; j++) {
      float oj = 0.f;
#pragma unroll
      for (int m = 0; m < 8; m++) oj += p[m] * sq[m * 100 + 64 + hd * 8 + j];
      o[n * 33 + hd * 8 + j] = oj * inv;
    }
  }
  __syncthreads();
  float a[8];
  float pbc = pb[lane];
#pragma unroll
  for (int n = 0; n < 8; n++) a[n] = pbc;
  for (int k = 0; k < 32; k++) {
    float w = pw[k * 64 + lane];
#pragma unroll
    for (int n = 0; n < 8; n++) a[n] += o[n * 33 + k] * w;
  }
  long base = ((long)b * 100352 + rr) * 64 + lane;
#pragma unroll
  for (int n = 0; n < 8; n++) acc[base + (long)n * 802816] += a[n];
}

// ---------------- MFMA implicit-GEMM 3x3x3 conv (7 tiles/wave, bf16 residuals) --
__global__ __launch_bounds__(64) void k_convm(const u16* __restrict__ in, const u16* __restrict__ wb,
    const float* __restrict__ bias, int mode,
    const u16* __restrict__ res1, const u16* __restrict__ res2,
    const float* __restrict__ accb, float* __restrict__ dout, u16* __restrict__ outb) {
  int row = blockIdx.x;
  int hh = row % 112, bz = row / 112;
  int d = bz & 7, bb = bz >> 3;
  long prow = (long)row * 112;
  int l = threadIdx.x, lm = l & 15, lk = l >> 4;
  f32x4 acc[7][2];
#pragma unroll
  for (int t = 0; t < 7; t++) { acc[t][0] = (f32x4){0.f,0.f,0.f,0.f}; acc[t][1] = (f32x4){0.f,0.f,0.f,0.f}; }
  for (int kd = 0; kd < 3; kd++) {
    int zd = d + kd - 1;
    if (zd < 0 || zd > 7) continue;
    for (int kh = 0; kh < 3; kh++) {
      int yy = hh + kh - 1;
      if (yy < 0 || yy > 111) continue;
      const u16* ip = in + ((long)((bb * 8 + zd) * 112 + yy)) * 112 * 32;
      int kkb = kd * 9 + kh * 3;
      s16x8 B0[3], B1[3];
#pragma unroll
      for (int kw = 0; kw < 3; kw++) {
        const u16* wp = wb + (kkb + kw) * 1024 + lk * 8;
        B0[kw] = *(const s16x8*)(wp + lm * 32);
        B1[kw] = *(const s16x8*)(wp + (16 + lm) * 32);
      }
#pragma unroll
      for (int t = 0; t < 7; t++) {
#pragma unroll
        for (int kw = 0; kw < 3; kw++) {
          int w = t * 16 + lm + kw - 1;
          s16x8 A = {};
          if ((unsigned)w < 112u) A = *(const s16x8*)(ip + (long)w * 32 + lk * 8);
          acc[t][0] = __builtin_amdgcn_mfma_f32_16x16x32_bf16(A, B0[kw], acc[t][0], 0, 0, 0);
          acc[t][1] = __builtin_amdgcn_mfma_f32_16x16x32_bf16(A, B1[kw], acc[t][1], 0, 0, 0);
        }
      }
    }
  }
  float b0 = bias[lm], b1 = bias[16 + lm];
#pragma unroll
  for (int t = 0; t < 7; t++) {
#pragma unroll
    for (int r = 0; r < 4; r++) {
      long pos = prow + t * 16 + lk * 4 + r;
      float v0 = acc[t][0][r] + b0;
      float v1 = acc[t][1][r] + b1;
      if (mode == 1) {
        v0 = v0 > 0.f ? v0 : 0.01f * v0;
        v1 = v1 > 0.f ? v1 : 0.01f * v1;
        outb[pos * 32 + lm] = f2b(v0);
        outb[pos * 32 + 16 + lm] = f2b(v1);
      } else if (mode == 2) {
        float y0 = v0 + b2f(res1[pos * 32 + lm]);
        float y1v = v1 + b2f(res1[pos * 32 + 16 + lm]);
        dout[pos * 64 + lm] = accb[pos * 64 + lm] + y0;
        dout[pos * 64 + 16 + lm] = accb[pos * 64 + 16 + lm] + y1v;
        float t0 = b2f(res2[pos * 32 + lm]) + y0;
        float t1 = b2f(res2[pos * 32 + 16 + lm]) + y1v;
        outb[pos * 32 + lm] = f2b(t0);
        outb[pos * 32 + 16 + lm] = f2b(t1);
      } else {
        float y0 = v0 + b2f(res1[pos * 32 + lm]);
        float y1v = v1 + b2f(res1[pos * 32 + 16 + lm]);
        dout[pos * 64 + 32 + lm] = accb[pos * 64 + 32 + lm] + y0;
        dout[pos * 64 + 48 + lm] = accb[pos * 64 + 48 + lm] + y1v;
      }
    }
  }
}

extern "C" void kernel_launch(void* const* d_in, const int* in_sizes, int n_in,
                              void* d_out, int out_size, void* d_ws, size_t ws_size,
                              hipStream_t stream) {
  const float* x        = (const float*)d_in[0];
  // d_in[1] mask_matrix: unused (all zeros; reference never applies it)
  const float* g1       = (const float*)d_in[2];
  const float* b1       = (const float*)d_in[3];
  const float* rpb_s    = (const float*)d_in[4];
  const float* qkv_w_s  = (const float*)d_in[5];
  const float* qkv_b_s  = (const float*)d_in[6];
  const float* proj_w_s = (const float*)d_in[7];
  const float* proj_b_s = (const float*)d_in[8];
  const float* rpb_t    = (const float*)d_in[9];
  const float* qkv_w_t  = (const float*)d_in[10];
  const float* qkv_b_t  = (const float*)d_in[11];
  const float* proj_w_t = (const float*)d_in[12];
  const float* proj_b_t = (const float*)d_in[13];
  const float* g2       = (const float*)d_in[14];
  const float* b2       = (const float*)d_in[15];
  const float* c1w = (const float*)d_in[16];
  const float* c1b = (const float*)d_in[17];
  const float* c2w = (const float*)d_in[18];
  const float* c2b = (const float*)d_in[19];
  const float* c3w = (const float*)d_in[20];
  const float* c3b = (const float*)d_in[21];
  const float* c4w = (const float*)d_in[22];
  const float* c4b = (const float*)d_in[23];

  // workspace (fp32 elems): acc(12.8M) | hbuf(12.8M) | creg(19.27M)
  float* acc  = (float*)d_ws;
  float* hbuf = acc + 12845056;
  float* creg = hbuf + 12845056;
  u16* Qg = (u16*)creg;
  u16* Kg = Qg + 12845056;
  u16* Vg = Kg + 12845056;
  u16* Tt = (u16*)hbuf;                // temporal qkv (38.5MB in hbuf)
  // conv-phase creg layout (written only after Qg/Kg/Vg are dead):
  u16* x1b = (u16*)creg;               // h2 bf16 ch0..31
  u16* t_b = x1b + 6422528;
  u16* x2b = t_b + 6422528;
  u16* x2h = x2b + 6422528;            // h2 bf16 ch32..63
  u16* WB  = x2h + 6422528;            // overlaps Vg -> packed only after sattn3
  float* dout = (float*)d_out;
  // d_out scratch (dead once conv2 writes dout):
  u16* pwb = (u16*)d_out;              // 4096 u16
  u16* twb = (u16*)d_out + 4096;       // 6144 u16
  u16* swb = (u16*)d_out + 10240;      // 12288 u16
  float* Bt = (float*)d_out + 11264;   // 50176 f32

  // 0. small prepacks + bias table (d_out scratch only)
  k_prep<<<284, 256, 0, stream>>>(proj_w_s, pwb, qkv_w_t, twb, qkv_w_s, swb, rpb_s, Bt);
  // 1. fused LN1 + spatial qkv + temporal qkv; acc = x
  k_fused1<<<3136, 256, 0, stream>>>(x, g1, b1, swb, qkv_b_s, twb, qkv_b_t,
                                     acc, Qg, Kg, Vg, Tt);
  // 2. MFMA spatial attention + fused projection, acc +=
  k_sattn3<<<2048, 512, 0, stream>>>(Qg, Kg, Vg, Bt, pwb, proj_b_s, acc);
  // 3. conv weight prepack — AFTER sattn3 (WB region overlaps Vg)
  k_wprep<<<432, 256, 0, stream>>>(c1w, c2w, c3w, c4w, WB);
  // 4. temporal attention + proj, acc +=
  k_tattn2<<<6272, 256, 0, stream>>>(Tt, rpb_t, proj_w_t, proj_b_t, acc);
  // 5. LN2: h2 -> x1b (ch0..31) + x2h (ch32..63), bf16 only
  k_ln2<<<50176, 256, 0, stream>>>(acc, g2, b2, x1b, x2h);
  // 6. conv path 1: t = lrelu(conv(x1)) -> t_b bf16
  k_convm<<<1792, 64, 0, stream>>>(x1b, WB, c1b, 1, nullptr, nullptr, nullptr, nullptr, t_b);
  // 7. conv2: y1 = x1 + conv(t); dout ch0..31 = acc + y1; x2b = bf16(x2h + y1)
  k_convm<<<1792, 64, 0, stream>>>(t_b, WB + 27648, c2b, 2, x1b, x2h, acc, dout, x2b);
  // 8. conv path 2: t = lrelu(conv(x2b)) -> t_b bf16
  k_convm<<<1792, 64, 0, stream>>>(x2b, WB + 2 * 27648, c3b, 1, nullptr, nullptr, nullptr, nullptr, t_b);
  // 9. conv4: y2 = x2 + conv(t); dout ch32..63 = acc + y2
  k_convm<<<1792, 64, 0, stream>>>(t_b, WB + 3 * 27648, c4b, 4, x2b, nullptr, acc, dout, nullptr);
}

// Round 21
// 420.060 us; speedup vs baseline: 1.0201x; 1.0201x over previous
//
#include <hip/hip_runtime.h>
#include <hip/hip_bf16.h>

typedef unsigned short u16;
typedef unsigned int u32;
typedef __attribute__((ext_vector_type(8))) short s16x8;
typedef __attribute__((ext_vector_type(4))) float f32x4;

__device__ __forceinline__ u16 f2b(float v) {
  u32 bits = __float_as_uint(v);
  bits += 0x7fffu + ((bits >> 16) & 1u);
  return (u16)(bits >> 16);
}
__device__ __forceinline__ float b2f(u16 u) { return __uint_as_float(((u32)u) << 16); }
__device__ __forceinline__ float bflo(u32 w) { return __uint_as_float(w << 16); }
__device__ __forceinline__ float bfhi(u32 w) { return __uint_as_float(w & 0xffff0000u); }

// ---------------- LayerNorm (LN2): bf16-only outputs x1b (ch0..31), x2h (ch32..63)
__global__ __launch_bounds__(256) void k_ln2(const float* __restrict__ x, const float* __restrict__ g,
    const float* __restrict__ b, u16* __restrict__ x1b, u16* __restrict__ x2h) {
  int token = blockIdx.x * 4 + (threadIdx.x >> 6);
  int lane = threadIdx.x & 63;
  long base = (long)token * 64 + lane;
  float v = x[base];
  float s = v;
#pragma unroll
  for (int o = 32; o; o >>= 1) s += __shfl_xor(s, o);
  float m = s * 0.015625f;
  float d = v - m;
  float q = d * d;
#pragma unroll
  for (int o = 32; o; o >>= 1) q += __shfl_xor(q, o);
  float r = rsqrtf(q * 0.015625f + 1e-5f);
  float hv = d * r * g[lane] + b[lane];
  u16 hb = f2b(hv);
  if (lane < 32) x1b[(long)token * 32 + lane] = hb;
  else x2h[(long)token * 32 + lane - 32] = hb;
}

// ---------------- Small prepacks (d_out scratch): pwb|twb|swb|Bt ----------------
__global__ __launch_bounds__(256) void k_prep(const float* __restrict__ pw, u16* __restrict__ pwb,
    const float* __restrict__ tqw, u16* __restrict__ twb,
    const float* __restrict__ sqw, u16* __restrict__ swb,
    const float* __restrict__ rpb, float* __restrict__ Bt) {
  int i = blockIdx.x * 256 + threadIdx.x;
  if (i < 4096) {
    int r = i & 7, q = i >> 3;
    int col = q & 15; q >>= 4;
    int lk = q & 1; q >>= 1;
    int nt = q & 3, hd = q >> 2;
    pwb[i] = f2b(pw[(hd * 16 + lk * 8 + r) * 64 + nt * 16 + col]);
  } else if (i < 10240) {
    int j = i - 4096;
    int kk = j & 31, q = j >> 5;
    int lm = q & 15, ksnt = q >> 4;
    int ks = ksnt & 1, nt = ksnt >> 1;
    twb[j] = f2b(tqw[(ks * 32 + kk) * 96 + nt * 16 + lm]);
  } else if (i < 22528) {
    int j = i - 10240;
    int kk = j & 31, q = j >> 5;
    int lm = q & 15, ksnt = q >> 4;
    int ks = ksnt & 1, nt = ksnt >> 1;
    swb[j] = f2b(sqw[(ks * 32 + kk) * 192 + nt * 16 + lm]);
  } else {
    int j = i - 22528;
    int m = j % 112, q = j / 112;
    int n = q % 112, hd = q / 112;
    float v = -1e30f;
    if (n < 98 && m < 98) {
      int dzn = n / 49, rn = n % 49, hyn = rn / 7, wxn = rn % 7;
      int dzm = m / 49, rm = m % 49, hym = rm / 7, wxm = rm % 7;
      int idx = (dzn - dzm + 1) * 169 + (hyn - hym + 6) * 13 + (wxn - wxm + 6);
      v = rpb[idx * 4 + hd];
    }
    Bt[j] = v;
  }
}

// ---------------- Conv weight prepack: MUST run after Vg is dead ----------------
__global__ __launch_bounds__(256) void k_wprep(const float* __restrict__ w0, const float* __restrict__ w1,
    const float* __restrict__ w2, const float* __restrict__ w3, u16* __restrict__ WB) {
  int j = blockIdx.x * 256 + threadIdx.x;   // < 110592
  int c = j / 27648, j2 = j - c * 27648;
  const float* src = c == 0 ? w0 : c == 1 ? w1 : c == 2 ? w2 : w3;
  int co = j2 / 864, rem = j2 - co * 864, ci = rem / 27, kk = rem - ci * 27;
  WB[c * 27648 + kk * 1024 + co * 32 + ci] = f2b(src[j2]);
}

// ---------------- Fused LN1 + spatial qkv + temporal qkv (MFMA) -----------------
__global__ __launch_bounds__(256) void k_fused1(const float* __restrict__ x,
    const float* __restrict__ g1, const float* __restrict__ b1,
    const u16* __restrict__ swb, const float* __restrict__ sqb,
    const u16* __restrict__ twb, const float* __restrict__ tqb,
    float* __restrict__ acc, u16* __restrict__ Qg, u16* __restrict__ Kg,
    u16* __restrict__ Vg, u16* __restrict__ T) {
  int l = threadIdx.x & 63, wv = threadIdx.x >> 6;
  int lm = l & 15, lk = l >> 4;
  long t0 = (long)blockIdx.x * 64 + wv * 16;
  long tok = t0 + lm;
  const float* xp = x + tok * 64 + lk * 8;
  float* ap = acc + tok * 64 + lk * 8;
  float va[16];
  float s = 0.f;
#pragma unroll
  for (int ks = 0; ks < 2; ks++) {
    float4 a0 = *(const float4*)(xp + ks * 32);
    float4 a1 = *(const float4*)(xp + ks * 32 + 4);
    *(float4*)(ap + ks * 32) = a0;          // acc = x
    *(float4*)(ap + ks * 32 + 4) = a1;
    va[ks * 8 + 0] = a0.x; va[ks * 8 + 1] = a0.y; va[ks * 8 + 2] = a0.z; va[ks * 8 + 3] = a0.w;
    va[ks * 8 + 4] = a1.x; va[ks * 8 + 5] = a1.y; va[ks * 8 + 6] = a1.z; va[ks * 8 + 7] = a1.w;
    s += a0.x + a0.y + a0.z + a0.w + a1.x + a1.y + a1.z + a1.w;
  }
  s += __shfl_xor(s, 16); s += __shfl_xor(s, 32);
  float m = s * 0.015625f;
  float q = 0.f;
#pragma unroll
  for (int j = 0; j < 16; j++) { float d = va[j] - m; q += d * d; }
  q += __shfl_xor(q, 16); q += __shfl_xor(q, 32);
  float r = rsqrtf(q * 0.015625f + 1e-5f);
  s16x8 A[2];
#pragma unroll
  for (int ks = 0; ks < 2; ks++) {
    float4 g0 = *(const float4*)(g1 + ks * 32 + lk * 8);
    float4 g4 = *(const float4*)(g1 + ks * 32 + lk * 8 + 4);
    float4 c0 = *(const float4*)(b1 + ks * 32 + lk * 8);
    float4 c4 = *(const float4*)(b1 + ks * 32 + lk * 8 + 4);
    s16x8 a;
    a[0] = (short)f2b((va[ks * 8 + 0] - m) * r * g0.x + c0.x);
    a[1] = (short)f2b((va[ks * 8 + 1] - m) * r * g0.y + c0.y);
    a[2] = (short)f2b((va[ks * 8 + 2] - m) * r * g0.z + c0.z);
    a[3] = (short)f2b((va[ks * 8 + 3] - m) * r * g0.w + c0.w);
    a[4] = (short)f2b((va[ks * 8 + 4] - m) * r * g4.x + c4.x);
    a[5] = (short)f2b((va[ks * 8 + 5] - m) * r * g4.y + c4.y);
    a[6] = (short)f2b((va[ks * 8 + 6] - m) * r * g4.z + c4.z);
    a[7] = (short)f2b((va[ks * 8 + 7] - m) * r * g4.w + c4.w);
    A[ks] = a;
  }
  f32x4 C[12], D[6];
#pragma unroll
  for (int nt = 0; nt < 12; nt++) C[nt] = (f32x4){0.f, 0.f, 0.f, 0.f};
#pragma unroll
  for (int nt = 0; nt < 6; nt++) D[nt] = (f32x4){0.f, 0.f, 0.f, 0.f};
#pragma unroll
  for (int ks = 0; ks < 2; ks++) {
#pragma unroll
    for (int nt = 0; nt < 12; nt++) {
      s16x8 B = *(const s16x8*)&swb[((nt * 2 + ks) * 16 + lm) * 32 + lk * 8];
      C[nt] = __builtin_amdgcn_mfma_f32_16x16x32_bf16(A[ks], B, C[nt], 0, 0, 0);
    }
#pragma unroll
    for (int nt = 0; nt < 6; nt++) {
      s16x8 B = *(const s16x8*)&twb[((nt * 2 + ks) * 16 + lm) * 32 + lk * 8];
      D[nt] = __builtin_amdgcn_mfma_f32_16x16x32_bf16(A[ks], B, D[nt], 0, 0, 0);
    }
  }
  float sbv[12], tbv[6];
#pragma unroll
  for (int nt = 0; nt < 12; nt++) sbv[nt] = sqb[nt * 16 + lm];
#pragma unroll
  for (int nt = 0; nt < 6; nt++) tbv[nt] = tqb[nt * 16 + lm];
#pragma unroll
  for (int r4 = 0; r4 < 4; r4++) {
    long t = t0 + lk * 4 + r4;
    int b = (int)(t / 100352); int r1 = (int)(t - (long)b * 100352);
    int d = r1 / 12544; int r2 = r1 - d * 12544;
    int hy = r2 / 112, wx = r2 - hy * 112;
    int d0 = d >> 1, dz = d & 1, h0 = hy / 7, oy = hy - h0 * 7, w0 = wx / 7, ox = wx - w0 * 7;
    int wi = ((b * 4 + d0) * 16 + h0) * 16 + w0;
    int n = dz * 49 + oy * 7 + ox;
    long sbase = (long)(wi * 4) * 1568 + n * 16 + lm;
#pragma unroll
    for (int nt = 0; nt < 12; nt++) {
      int part = nt >> 2, hd = nt & 3;
      float v = C[nt][r4] + sbv[nt];
      long o = sbase + hd * 1568;
      if (part == 0) Qg[o] = f2b(v * 0.25f);
      else if (part == 1) Kg[o] = f2b(v);
      else Vg[o] = f2b(v);
    }
    long sidx = ((long)(b * 12544 + r2) * 8 + d) * 96;
#pragma unroll
    for (int nt = 0; nt < 6; nt++) {
      float v = D[nt][r4] + tbv[nt];
      if (nt < 2) v *= 0.25f;
      T[sidx + nt * 16 + lm] = f2b(v);
    }
  }
}

// ---------------- MFMA spatial attention + fused projection ---------------------
// K,V staged in LDS; Q fragment direct from global (round-17/19 proven, ~112us)
__global__ __launch_bounds__(512) void k_sattn3(const u16* __restrict__ Qg, const u16* __restrict__ Kg,
    const u16* __restrict__ Vg, const float* __restrict__ Bt, const u16* __restrict__ pwb,
    const float* __restrict__ pb, float* __restrict__ accg) {
  __shared__ __align__(16) u16 sK[112 * 24];
  __shared__ __align__(16) u16 sVt[16 * 136];
  __shared__ __align__(16) u16 sP[112 * 120 + 32];
  __shared__ __align__(16) u16 sO[112 * 24];
  int tid = threadIdx.x;
  int wi = blockIdx.x;
  int l = tid & 63, wv = tid >> 6;
  int lm = l & 15, lk = l >> 4;

  for (int i = tid; i < 336; i += 512) { sK[2352 + i] = 0; }
  for (int i = tid; i < 224; i += 512) { sVt[(i / 14) * 136 + 98 + (i % 14)] = 0; }

  int mt = wv;
  bool act = mt < 7;
  int baserow = mt * 16 + lk * 4;
  int qrow = mt * 16 + lm;
  f32x4 po[4];
#pragma unroll
  for (int b = 0; b < 4; b++) po[b] = (f32x4){0.f, 0.f, 0.f, 0.f};

  for (int hd = 0; hd < 4; hd++) {
    __syncthreads();
    long base = (long)(wi * 4 + hd) * 1568;
    const u32* kp = (const u32*)(Kg + base);
    const u32* vp = (const u32*)(Vg + base);
    for (int i = tid; i < 784; i += 512) {
      u32 v = kp[i];
      int n = i >> 3, j2 = (i & 7) * 2;
      *(u32*)&sK[n * 24 + j2] = v;
    }
    for (int i = tid; i < 784; i += 512) {
      u32 v = vp[i];
      int n = i >> 3, j2 = (i & 7) * 2;
      sVt[j2 * 136 + n] = (u16)(v & 0xffffu);
      sVt[(j2 + 1) * 136 + n] = (u16)(v >> 16);
    }
    __syncthreads();
    if (!act) continue;

    s16x8 Aq = {};
    if (qrow < 98 && lk < 2) Aq = *(const s16x8*)(Qg + base + qrow * 16 + lk * 8);
    f32x4 S[7];
#pragma unroll
    for (int nt = 0; nt < 7; nt++) {
      s16x8 Bk = {};
      if (lk < 2) Bk = *(const s16x8*)&sK[(nt * 16 + lm) * 24 + lk * 8];
      S[nt] = __builtin_amdgcn_mfma_f32_16x16x32_bf16(Aq, Bk, (f32x4){0.f, 0.f, 0.f, 0.f}, 0, 0, 0);
    }
    const float* bt = Bt + hd * 12544 + baserow * 112 + lm;
    float mx0 = -3e38f, mx1 = -3e38f, mx2 = -3e38f, mx3 = -3e38f;
#pragma unroll
    for (int nt = 0; nt < 7; nt++) {
      S[nt][0] += bt[nt * 16];
      S[nt][1] += bt[112 + nt * 16];
      S[nt][2] += bt[224 + nt * 16];
      S[nt][3] += bt[336 + nt * 16];
      mx0 = fmaxf(mx0, S[nt][0]); mx1 = fmaxf(mx1, S[nt][1]);
      mx2 = fmaxf(mx2, S[nt][2]); mx3 = fmaxf(mx3, S[nt][3]);
    }
#pragma unroll
    for (int off = 1; off < 16; off <<= 1) {
      mx0 = fmaxf(mx0, __shfl_xor(mx0, off));
      mx1 = fmaxf(mx1, __shfl_xor(mx1, off));
      mx2 = fmaxf(mx2, __shfl_xor(mx2, off));
      mx3 = fmaxf(mx3, __shfl_xor(mx3, off));
    }
    float s0 = 0.f, s1 = 0.f, s2 = 0.f, s3 = 0.f;
#pragma unroll
    for (int nt = 0; nt < 7; nt++) {
      S[nt][0] = __expf(S[nt][0] - mx0); s0 += S[nt][0];
      S[nt][1] = __expf(S[nt][1] - mx1); s1 += S[nt][1];
      S[nt][2] = __expf(S[nt][2] - mx2); s2 += S[nt][2];
      S[nt][3] = __expf(S[nt][3] - mx3); s3 += S[nt][3];
    }
#pragma unroll
    for (int off = 1; off < 16; off <<= 1) {
      s0 += __shfl_xor(s0, off); s1 += __shfl_xor(s1, off);
      s2 += __shfl_xor(s2, off); s3 += __shfl_xor(s3, off);
    }
    float i0 = 1.f / s0, i1 = 1.f / s1, i2 = 1.f / s2, i3 = 1.f / s3;
#pragma unroll
    for (int nt = 0; nt < 7; nt++) {
      int c = nt * 16 + lm;
      sP[(baserow + 0) * 120 + c] = f2b(S[nt][0] * i0);
      sP[(baserow + 1) * 120 + c] = f2b(S[nt][1] * i1);
      sP[(baserow + 2) * 120 + c] = f2b(S[nt][2] * i2);
      sP[(baserow + 3) * 120 + c] = f2b(S[nt][3] * i3);
    }
    int rowoff = (mt * 16 + lm) * 120;
    f32x4 pv = (f32x4){0.f, 0.f, 0.f, 0.f};
#pragma unroll
    for (int ks = 0; ks < 3; ks++) {
      s16x8 Ap = *(const s16x8*)&sP[rowoff + ks * 32 + lk * 8];
      s16x8 Bv = *(const s16x8*)&sVt[lm * 136 + ks * 32 + lk * 8];
      pv = __builtin_amdgcn_mfma_f32_16x16x32_bf16(Ap, Bv, pv, 0, 0, 0);
    }
    {
      s16x8 Ap = {}, Bv = {};
      if (lk < 2) {
        Ap = *(const s16x8*)&sP[rowoff + 96 + lk * 8];
        Bv = *(const s16x8*)&sVt[lm * 136 + 96 + lk * 8];
      }
      pv = __builtin_amdgcn_mfma_f32_16x16x32_bf16(Ap, Bv, pv, 0, 0, 0);
    }
#pragma unroll
    for (int r = 0; r < 4; r++) sO[(baserow + r) * 24 + lm] = f2b(pv[r]);
    s16x8 Ao = {};
    if (lk < 2) Ao = *(const s16x8*)&sO[(mt * 16 + lm) * 24 + lk * 8];
#pragma unroll
    for (int nt = 0; nt < 4; nt++) {
      s16x8 Bw = {};
      if (lk < 2) Bw = *(const s16x8*)&pwb[((((hd * 4 + nt) * 2 + lk) * 16 + lm) * 8)];
      po[nt] = __builtin_amdgcn_mfma_f32_16x16x32_bf16(Ao, Bw, po[nt], 0, 0, 0);
    }
  }
  if (act) {
    int b = wi >> 10, d0 = (wi >> 8) & 3, h0 = (wi >> 4) & 15, w0 = wi & 15;
    float pbv[4];
#pragma unroll
    for (int nt = 0; nt < 4; nt++) pbv[nt] = pb[nt * 16 + lm];
#pragma unroll
    for (int r = 0; r < 4; r++) {
      int n = mt * 16 + lk * 4 + r;
      if (n >= 98) continue;
      int dz = n / 49, rr = n - dz * 49, oy = rr / 7, ox = rr - oy * 7;
      long p = ((long)(b * 8 + d0 * 2 + dz) * 112 + (h0 * 7 + oy)) * 112 + (w0 * 7 + ox);
      float* ap = accg + p * 64;
#pragma unroll
      for (int nt = 0; nt < 4; nt++) {
        int col = nt * 16 + lm;
        ap[col] += po[nt][r] + pbv[nt];
      }
    }
  }
}

// ---------------- Temporal attention (per pixel-seq, D=8) + proj, acc += --------
__global__ __launch_bounds__(256) void k_tattn2(const u16* __restrict__ T, const float* __restrict__ rpbt,
    const float* __restrict__ pw, const float* __restrict__ pb, float* __restrict__ acc) {
  __shared__ float sm[4][1064];   // sq 8x100, o 8x33
  int wv = threadIdx.x >> 6, lane = threadIdx.x & 63;
  int s = blockIdx.x * 4 + wv;
  int b = s / 12544, rr = s - b * 12544;
  float* sq = sm[wv];
  float* o = sq + 800;
  const u32* Tp = (const u32*)(T + (long)s * 768);
  for (int i = lane; i < 192; i += 64) {
    u32 lo = Tp[i * 2], hi = Tp[i * 2 + 1];
    int d = i / 24, base = (i - d * 24) * 4;
    float* dst = sq + d * 100 + base;
    dst[0] = bflo(lo); dst[1] = bfhi(lo); dst[2] = bflo(hi); dst[3] = bfhi(hi);
  }
  __syncthreads();
  if (lane < 32) {
    int hd = lane >> 3, n = lane & 7;
    const float* qr = sq + n * 100 + hd * 8;
    float p[8];
    float mx = -3e38f;
#pragma unroll
    for (int m = 0; m < 8; m++) {
      const float* kr = sq + m * 100 + 32 + hd * 8;
      float sc = 0.f;
#pragma unroll
      for (int e = 0; e < 8; e++) sc += qr[e] * kr[e];
      sc += rpbt[(n - m + 7) * 4 + hd];
      p[m] = sc; mx = fmaxf(mx, sc);
    }
    float sum = 0.f;
#pragma unroll
    for (int m = 0; m < 8; m++) { p[m] = __expf(p[m] - mx); sum += p[m]; }
    float inv = 1.f / sum;
#pragma unroll
    for (int j = 0; j < 8; j++) {
      float oj = 0.f;
#pragma unroll
      for (int m = 0; m < 8; m++) oj += p[m] * sq[m * 100 + 64 + hd * 8 + j];
      o[n * 33 + hd * 8 + j] = oj * inv;
    }
  }
  __syncthreads();
  float a[8];
  float pbc = pb[lane];
#pragma unroll
  for (int n = 0; n < 8; n++) a[n] = pbc;
  for (int k = 0; k < 32; k++) {
    float w = pw[k * 64 + lane];
#pragma unroll
    for (int n = 0; n < 8; n++) a[n] += o[n * 33 + k] * w;
  }
  long base = ((long)b * 100352 + rr) * 64 + lane;
#pragma unroll
  for (int n = 0; n < 8; n++) acc[base + (long)n * 802816] += a[n];
}

// ---------------- MFMA implicit-GEMM 3x3x3 conv (7 tiles/wave, bf16 residuals) --
__global__ __launch_bounds__(64) void k_convm(const u16* __restrict__ in, const u16* __restrict__ wb,
    const float* __restrict__ bias, int mode,
    const u16* __restrict__ res1, const u16* __restrict__ res2,
    const float* __restrict__ accb, float* __restrict__ dout, u16* __restrict__ outb) {
  int row = blockIdx.x;
  int hh = row % 112, bz = row / 112;
  int d = bz & 7, bb = bz >> 3;
  long prow = (long)row * 112;
  int l = threadIdx.x, lm = l & 15, lk = l >> 4;
  f32x4 acc[7][2];
#pragma unroll
  for (int t = 0; t < 7; t++) { acc[t][0] = (f32x4){0.f,0.f,0.f,0.f}; acc[t][1] = (f32x4){0.f,0.f,0.f,0.f}; }
  for (int kd = 0; kd < 3; kd++) {
    int zd = d + kd - 1;
    if (zd < 0 || zd > 7) continue;
    for (int kh = 0; kh < 3; kh++) {
      int yy = hh + kh - 1;
      if (yy < 0 || yy > 111) continue;
      const u16* ip = in + ((long)((bb * 8 + zd) * 112 + yy)) * 112 * 32;
      int kkb = kd * 9 + kh * 3;
      s16x8 B0[3], B1[3];
#pragma unroll
      for (int kw = 0; kw < 3; kw++) {
        const u16* wp = wb + (kkb + kw) * 1024 + lk * 8;
        B0[kw] = *(const s16x8*)(wp + lm * 32);
        B1[kw] = *(const s16x8*)(wp + (16 + lm) * 32);
      }
#pragma unroll
      for (int t = 0; t < 7; t++) {
#pragma unroll
        for (int kw = 0; kw < 3; kw++) {
          int w = t * 16 + lm + kw - 1;
          s16x8 A = {};
          if ((unsigned)w < 112u) A = *(const s16x8*)(ip + (long)w * 32 + lk * 8);
          acc[t][0] = __builtin_amdgcn_mfma_f32_16x16x32_bf16(A, B0[kw], acc[t][0], 0, 0, 0);
          acc[t][1] = __builtin_amdgcn_mfma_f32_16x16x32_bf16(A, B1[kw], acc[t][1], 0, 0, 0);
        }
      }
    }
  }
  float b0 = bias[lm], b1 = bias[16 + lm];
#pragma unroll
  for (int t = 0; t < 7; t++) {
#pragma unroll
    for (int r = 0; r < 4; r++) {
      long pos = prow + t * 16 + lk * 4 + r;
      float v0 = acc[t][0][r] + b0;
      float v1 = acc[t][1][r] + b1;
      if (mode == 1) {
        v0 = v0 > 0.f ? v0 : 0.01f * v0;
        v1 = v1 > 0.f ? v1 : 0.01f * v1;
        outb[pos * 32 + lm] = f2b(v0);
        outb[pos * 32 + 16 + lm] = f2b(v1);
      } else if (mode == 2) {
        float y0 = v0 + b2f(res1[pos * 32 + lm]);
        float y1v = v1 + b2f(res1[pos * 32 + 16 + lm]);
        dout[pos * 64 + lm] = accb[pos * 64 + lm] + y0;
        dout[pos * 64 + 16 + lm] = accb[pos * 64 + 16 + lm] + y1v;
        float t0 = b2f(res2[pos * 32 + lm]) + y0;
        float t1 = b2f(res2[pos * 32 + 16 + lm]) + y1v;
        outb[pos * 32 + lm] = f2b(t0);
        outb[pos * 32 + 16 + lm] = f2b(t1);
      } else {
        float y0 = v0 + b2f(res1[pos * 32 + lm]);
        float y1v = v1 + b2f(res1[pos * 32 + 16 + lm]);
        dout[pos * 64 + 32 + lm] = accb[pos * 64 + 32 + lm] + y0;
        dout[pos * 64 + 48 + lm] = accb[pos * 64 + 48 + lm] + y1v;
      }
    }
  }
}

extern "C" void kernel_launch(void* const* d_in, const int* in_sizes, int n_in,
                              void* d_out, int out_size, void* d_ws, size_t ws_size,
                              hipStream_t stream) {
  const float* x        = (const float*)d_in[0];
  // d_in[1] mask_matrix: unused (all zeros; reference never applies it)
  const float* g1       = (const float*)d_in[2];
  const float* b1       = (const float*)d_in[3];
  const float* rpb_s    = (const float*)d_in[4];
  const float* qkv_w_s  = (const float*)d_in[5];
  const float* qkv_b_s  = (const float*)d_in[6];
  const float* proj_w_s = (const float*)d_in[7];
  const float* proj_b_s = (const float*)d_in[8];
  const float* rpb_t    = (const float*)d_in[9];
  const float* qkv_w_t  = (const float*)d_in[10];
  const float* qkv_b_t  = (const float*)d_in[11];
  const float* proj_w_t = (const float*)d_in[12];
  const float* proj_b_t = (const float*)d_in[13];
  const float* g2       = (const float*)d_in[14];
  const float* b2       = (const float*)d_in[15];
  const float* c1w = (const float*)d_in[16];
  const float* c1b = (const float*)d_in[17];
  const float* c2w = (const float*)d_in[18];
  const float* c2b = (const float*)d_in[19];
  const float* c3w = (const float*)d_in[20];
  const float* c3b = (const float*)d_in[21];
  const float* c4w = (const float*)d_in[22];
  const float* c4b = (const float*)d_in[23];

  // workspace (fp32 elems): acc(12.8M) | hbuf(12.8M) | creg(19.27M)
  float* acc  = (float*)d_ws;
  float* hbuf = acc + 12845056;
  float* creg = hbuf + 12845056;
  u16* Qg = (u16*)creg;
  u16* Kg = Qg + 12845056;
  u16* Vg = Kg + 12845056;
  u16* Tt = (u16*)hbuf;                // temporal qkv (38.5MB in hbuf)
  // conv-phase creg layout (written only after Qg/Kg/Vg are dead):
  u16* x1b = (u16*)creg;               // h2 bf16 ch0..31
  u16* t_b = x1b + 6422528;
  u16* x2b = t_b + 6422528;
  u16* x2h = x2b + 6422528;            // h2 bf16 ch32..63
  u16* WB  = x2h + 6422528;            // overlaps Vg -> packed only after sattn3
  float* dout = (float*)d_out;
  // d_out scratch (dead once conv2 writes dout):
  u16* pwb = (u16*)d_out;              // 4096 u16
  u16* twb = (u16*)d_out + 4096;       // 6144 u16
  u16* swb = (u16*)d_out + 10240;      // 12288 u16
  float* Bt = (float*)d_out + 11264;   // 50176 f32

  // 0. small prepacks + bias table (d_out scratch only)
  k_prep<<<284, 256, 0, stream>>>(proj_w_s, pwb, qkv_w_t, twb, qkv_w_s, swb, rpb_s, Bt);
  // 1. fused LN1 + spatial qkv + temporal qkv; acc = x
  k_fused1<<<3136, 256, 0, stream>>>(x, g1, b1, swb, qkv_b_s, twb, qkv_b_t,
                                     acc, Qg, Kg, Vg, Tt);
  // 2. MFMA spatial attention + fused projection, acc +=
  k_sattn3<<<2048, 512, 0, stream>>>(Qg, Kg, Vg, Bt, pwb, proj_b_s, acc);
  // 3. conv weight prepack — AFTER sattn3 (WB region overlaps Vg)
  k_wprep<<<432, 256, 0, stream>>>(c1w, c2w, c3w, c4w, WB);
  // 4. temporal attention + proj, acc +=
  k_tattn2<<<6272, 256, 0, stream>>>(Tt, rpb_t, proj_w_t, proj_b_t, acc);
  // 5. LN2: h2 -> x1b (ch0..31) + x2h (ch32..63), bf16 only
  k_ln2<<<50176, 256, 0, stream>>>(acc, g2, b2, x1b, x2h);
  // 6. conv path 1: t = lrelu(conv(x1)) -> t_b bf16
  k_convm<<<1792, 64, 0, stream>>>(x1b, WB, c1b, 1, nullptr, nullptr, nullptr, nullptr, t_b);
  // 7. conv2: y1 = x1 + conv(t); dout ch0..31 = acc + y1; x2b = bf16(x2h + y1)
  k_convm<<<1792, 64, 0, stream>>>(t_b, WB + 27648, c2b, 2, x1b, x2h, acc, dout, x2b);
  // 8. conv path 2: t = lrelu(conv(x2b)) -> t_b bf16
  k_convm<<<1792, 64, 0, stream>>>(x2b, WB + 2 * 27648, c3b, 1, nullptr, nullptr, nullptr, nullptr, t_b);
  // 9. conv4: y2 = x2 + conv(t); dout ch32..63 = acc + y2
  k_convm<<<1792, 64, 0, stream>>>(t_b, WB + 3 * 27648, c4b, 4, x2b, nullptr, acc, dout, nullptr);
}